// Round 4
// baseline (127.993 us; speedup 1.0000x reference)
//
#include <hip/hip_runtime.h>
#include <math.h>

// Tropical (max-plus) matmul: out[b,o] = max_k ( x[b,k] + W[o,k] )
// x: (2048,512) f32, W: (512,512) f32, out: (2048,512) f32.
//
// R3 post-mortem: LDS-staged GEMM structure stuck at ~36us (vs 10.2us LDS
// floor, 6.8us VALU floor); barriers expose latency, split-K added traffic.
// R4: NO LDS, NO barriers. Lane = output row, wave = 8 output cols.
// W pre-packed (1MB in ws) into per-wave contiguous k-paired strips read at
// wave-uniform addresses (-> s_load into SGPRs). Inner op is the pure VALU
// floor: v_pk_add_f32 + v_max3_f32, 2 instr per output per k-pair.
// Fixed ~51us of dur_us is harness d_ws re-poison + input restores.

typedef float f2v __attribute__((ext_vector_type(2)));
typedef float f4v __attribute__((ext_vector_type(4)));

#define B_ROWS 2048
#define K_DIM  512
#define O_DIM  512
#define NKP    (K_DIM / 2)    // 256 k-pairs
#define CPW    8              // cols per wave
#define NCB    (O_DIM / CPW)  // 64 col-blocks

// Wp[cb][kp][j] = { W[cb*8+j][2kp], W[cb*8+j][2kp+1] },  cb<64, kp<256, j<8.
// Each cb strip = 256*8 f2v = 16 KB contiguous, streamed by exactly one wave
// per row-block at uniform (per-wave) addresses.
__global__ __launch_bounds__(256) void pack_w(
    const float* __restrict__ W, f2v* __restrict__ Wp)
{
    const int idx = blockIdx.x * 256 + threadIdx.x;  // 0 .. 131071
    const int j  = idx & 7;
    const int kp = (idx >> 3) & (NKP - 1);
    const int cb = idx >> 11;
    const int col = cb * 8 + j;
    Wp[idx] = *(const f2v*)(W + (size_t)col * K_DIM + 2 * kp);
}

__global__ __launch_bounds__(256, 2) void tropical_main(
    const float* __restrict__ x, const f2v* __restrict__ Wp,
    float* __restrict__ out)
{
    const int t    = threadIdx.x;
    const int lane = t & 63;
    const int w    = __builtin_amdgcn_readfirstlane(t >> 6);  // wave id 0..3
    const int row  = blockIdx.x * 64 + lane;
    const int cb   = blockIdx.y * 4 + w;                      // col-block

    const f2v*   wp = Wp + (size_t)cb * (NKP * CPW);  // 16 KB uniform strip
    const float* xp = x + (size_t)row * K_DIM;

    float acc[CPW];
#pragma unroll
    for (int j = 0; j < CPW; ++j) acc[j] = -INFINITY;

    // 128 chunks of 2 k-pairs (4 k). Per chunk: 1 x dwordx4 (per-lane),
    // 32 W floats (wave-uniform -> 2x s_load_dwordx16), 32 VALU instrs.
#pragma unroll 4
    for (int c = 0; c < NKP / 2; ++c) {
        f4v xv = *(const f4v*)(xp + c * 4);
        f2v x0 = xv.xy;
        f2v x1 = xv.zw;
        const f2v* wv = wp + (size_t)c * 16;
#pragma unroll
        for (int j = 0; j < CPW; ++j) {
            f2v s = x0 + wv[j];                         // v_pk_add_f32
            acc[j] = fmaxf(acc[j], fmaxf(s.x, s.y));    // v_max3_f32
        }
#pragma unroll
        for (int j = 0; j < CPW; ++j) {
            f2v s = x1 + wv[8 + j];
            acc[j] = fmaxf(acc[j], fmaxf(s.x, s.y));
        }
    }

    float* op = out + (size_t)row * O_DIM + cb * CPW;
    f4v v0 = {acc[0], acc[1], acc[2], acc[3]};
    f4v v1 = {acc[4], acc[5], acc[6], acc[7]};
    *(f4v*)op = v0;
    *(f4v*)(op + 4) = v1;
}

// Never-taken fallback (ws too small): trivially correct direct kernel.
__global__ __launch_bounds__(256) void tropical_naive(
    const float* __restrict__ x, const float* __restrict__ W,
    float* __restrict__ out)
{
    const int o = blockIdx.x * 256 + threadIdx.x;  // 0 .. 2048*512-1
    const int col = o & (O_DIM - 1);
    const int row = o >> 9;
    const float* xr = x + (size_t)row * K_DIM;
    const float* wr = W + (size_t)col * K_DIM;
    float m = -INFINITY;
    for (int k = 0; k < K_DIM; ++k) m = fmaxf(m, xr[k] + wr[k]);
    out[o] = m;
}

extern "C" void kernel_launch(void* const* d_in, const int* in_sizes, int n_in,
                              void* d_out, int out_size, void* d_ws, size_t ws_size,
                              hipStream_t stream) {
    const float* x = (const float*)d_in[0];   // (2048, 512)
    const float* W = (const float*)d_in[1];   // (512, 512)
    float* out = (float*)d_out;               // (2048, 512)

    const size_t pack_bytes = (size_t)NCB * NKP * CPW * sizeof(f2v);  // 1 MB
    if (ws_size >= pack_bytes) {
        f2v* Wp = (f2v*)d_ws;
        pack_w<<<(NCB * NKP * CPW) / 256, 256, 0, stream>>>(W, Wp);
        dim3 grid(B_ROWS / 64, O_DIM / (CPW * 4));  // (32, 16) = 512 blocks
        tropical_main<<<grid, 256, 0, stream>>>(x, Wp, out);
    } else {
        tropical_naive<<<(B_ROWS * O_DIM) / 256, 256, 0, stream>>>(x, W, out);
    }
}

// Round 5
// 102.631 us; speedup vs baseline: 1.2471x; 1.2471x over previous
//
#include <hip/hip_runtime.h>
#include <math.h>

// Tropical (max-plus) matmul: out[b,o] = max_k ( x[b,k] + W[o,k] )
// x: (2048,512) f32, W: (512,512) f32, out: (2048,512) f32.
//
// R4 post-mortem: W strip loads stayed per-lane VMEM (not s_load) and x loads
// were lane-scattered (64 lines/instr) -> latency-bound, VALUBusy 22%.
// R5 structure: lane <-> output column, rows wave-uniform.
//   - W packed as Wt4[kq][o] (1 MB ws): lane reads are perfectly coalesced.
//   - x block strip (16 rows x 512 k = 32 KB) staged to LDS once, ONE barrier,
//     then barrier-free k-loop; all x reads are wave-uniform b128 broadcasts
//     (broadcast = conflict-free regardless of layout).
//   - Inner op: v_pk_add_f32 + v_max3_f32 = 1 instr per k-output (VALU floor
//     6.8 us). LDS:VALU = 1:8 instrs, VMEM 2 dwordx4 per 32 VALU.
//   - 512 blocks (2/CU), 8 waves/CU, no k-loop barriers -> pipelinable.
// Fixed ~51 us of dur_us is the harness's d_ws re-poison + input restores.

typedef float f2v __attribute__((ext_vector_type(2)));
typedef float f4v __attribute__((ext_vector_type(4)));

#define B_ROWS 2048
#define K_DIM  512
#define O_DIM  512
#define NKQ    (K_DIM / 4)   // 128 k-quads
#define RPB    16            // rows per block
#define CPB    128           // cols per block
#define RPW    4             // rows per wave

// Wt4[kq][o] = { W[o][4kq], W[o][4kq+1], W[o][4kq+2], W[o][4kq+3] }
__global__ __launch_bounds__(256) void pack_w(
    const f4v* __restrict__ W4, f4v* __restrict__ Wt4)
{
    const int idx = blockIdx.x * 256 + threadIdx.x;  // 0..65535
    const int kq = idx & (NKQ - 1);                  // fastest -> coalesced read
    const int o  = idx >> 7;
    Wt4[(size_t)kq * O_DIM + o] = W4[(size_t)o * NKQ + kq];
}

__global__ __launch_bounds__(256, 2) void tropical_main(
    const float* __restrict__ x, const f4v* __restrict__ Wt4,
    float* __restrict__ out)
{
    __shared__ f4v xs4[RPB * NKQ];  // 32 KB: 16 rows x 512 k

    const int t    = threadIdx.x;
    const int lane = t & 63;
    const int w    = t >> 6;                 // wave id 0..3 -> row group
    const int br   = blockIdx.x * RPB;
    const int bc   = blockIdx.y * CPB;

    // stage x strip -> LDS, coalesced; the only barrier in the kernel
    const f4v* xg4 = (const f4v*)x + (size_t)br * NKQ;
#pragma unroll
    for (int i = 0; i < (RPB * NKQ) / 256; ++i)   // 8 iters = 32 KB
        xs4[i * 256 + t] = xg4[i * 256 + t];
    __syncthreads();

    const f4v* xrb = xs4 + w * RPW * NKQ;    // this wave's 4 rows
    const f4v* wp  = Wt4 + bc + lane;        // col c0 = bc+lane; c1 = +64

    float acc[RPW][2];
#pragma unroll
    for (int r = 0; r < RPW; ++r) {
        acc[r][0] = -INFINITY;
        acc[r][1] = -INFINITY;
    }

#pragma unroll 4
    for (int kq = 0; kq < NKQ; ++kq) {
        f4v xr[RPW];
#pragma unroll
        for (int r = 0; r < RPW; ++r)
            xr[r] = xrb[r * NKQ + kq];              // ds_read_b128 broadcast
        const f4v w0 = wp[(size_t)kq * O_DIM];      // coalesced dwordx4
        const f4v w1 = wp[(size_t)kq * O_DIM + 64]; // coalesced dwordx4
#pragma unroll
        for (int r = 0; r < RPW; ++r) {
            f2v s;
            s = xr[r].xy + w0.xy;                       // v_pk_add_f32
            acc[r][0] = fmaxf(acc[r][0], fmaxf(s.x, s.y));  // v_max3_f32
            s = xr[r].zw + w0.zw;
            acc[r][0] = fmaxf(acc[r][0], fmaxf(s.x, s.y));
            s = xr[r].xy + w1.xy;
            acc[r][1] = fmaxf(acc[r][1], fmaxf(s.x, s.y));
            s = xr[r].zw + w1.zw;
            acc[r][1] = fmaxf(acc[r][1], fmaxf(s.x, s.y));
        }
    }

    // stores: coalesced dword per (row, col-half)
#pragma unroll
    for (int r = 0; r < RPW; ++r) {
        float* op = out + (size_t)(br + w * RPW + r) * O_DIM + bc + lane;
        op[0]  = acc[r][0];
        op[64] = acc[r][1];
    }
}

// Fallback (ws too small for the 1 MB pack): correct direct kernel.
__global__ __launch_bounds__(256) void tropical_naive(
    const float* __restrict__ x, const float* __restrict__ W,
    float* __restrict__ out)
{
    const int o = blockIdx.x * 256 + threadIdx.x;  // 0 .. 2048*512-1
    const int col = o & (O_DIM - 1);
    const int row = o >> 9;
    const float* xr = x + (size_t)row * K_DIM;
    const float* wr = W + (size_t)col * K_DIM;
    float m = -INFINITY;
    for (int k = 0; k < K_DIM; ++k) m = fmaxf(m, xr[k] + wr[k]);
    out[o] = m;
}

extern "C" void kernel_launch(void* const* d_in, const int* in_sizes, int n_in,
                              void* d_out, int out_size, void* d_ws, size_t ws_size,
                              hipStream_t stream) {
    const float* x = (const float*)d_in[0];   // (2048, 512)
    const float* W = (const float*)d_in[1];   // (512, 512)
    float* out = (float*)d_out;               // (2048, 512)

    const size_t pack_bytes = (size_t)NKQ * O_DIM * sizeof(f4v);  // 1 MB
    if (ws_size >= pack_bytes) {
        f4v* Wt4 = (f4v*)d_ws;
        pack_w<<<(NKQ * O_DIM) / 256, 256, 0, stream>>>((const f4v*)W, Wt4);
        dim3 grid(B_ROWS / RPB, O_DIM / CPB);  // (128, 4) = 512 blocks
        tropical_main<<<grid, 256, 0, stream>>>(x, Wt4, out);
    } else {
        tropical_naive<<<(B_ROWS * O_DIM) / 256, 256, 0, stream>>>(x, W, out);
    }
}